// Round 9
// baseline (1984.374 us; speedup 1.0000x reference)
//
#include <hip/hip_runtime.h>

#define NN 100000
#define NE 3200000
#define NG 256
#define H 32
#define CE 8                     // edges per chunk
#define NCH (NE / CE)            // 400000 chunks
#define SB ((NN + 255) / 256)    // 391 scan blocks

// Monotone bijection float -> u32 (order-preserving), so u32 max == float max.
__device__ __forceinline__ unsigned encf(float f) {
    unsigned u = __float_as_uint(f);
    return (u & 0x80000000u) ? ~u : (u | 0x80000000u);
}
__device__ __forceinline__ float decf(unsigned u) {
    return __uint_as_float((u & 0x80000000u) ? (u & 0x7fffffffu) : ~u);
}

// Flush an 8-wide slice run-max to global agg (enc domain, test-before-atomic).
// agg starts at enc(0): values <=0 never pass the test (folds relu + neginf fill).
__device__ __forceinline__ void flush8(unsigned* __restrict__ agg, int node,
                                       int slice, const float* m) {
    unsigned* ag = agg + (size_t)node * H + (slice << 3);
#pragma unroll
    for (int r = 0; r < 2; r++) {
        uint4 c = ((const uint4*)ag)[r];
        unsigned v0 = encf(m[4 * r + 0]);
        unsigned v1 = encf(m[4 * r + 1]);
        unsigned v2 = encf(m[4 * r + 2]);
        unsigned v3 = encf(m[4 * r + 3]);
        if (v0 > c.x) atomicMax(ag + 4 * r + 0, v0);
        if (v1 > c.y) atomicMax(ag + 4 * r + 1, v1);
        if (v2 > c.z) atomicMax(ag + 4 * r + 2, v2);
        if (v3 > c.w) atomicMax(ag + 4 * r + 3, v3);
    }
}

// init agg=enc(0), g=enc(0), hist=0. Grid covers NN*H = 3.2M.
__global__ __launch_bounds__(256) void k_init(unsigned* __restrict__ agg,
                                              unsigned* __restrict__ g,
                                              unsigned* __restrict__ hist) {
    int i = blockIdx.x * 256 + threadIdx.x;
    agg[i] = 0x80000000u;
    if (i < NG * H) g[i] = 0x80000000u;
    if (i < NN) hist[i] = 0u;
}

// Pack weights for wave-uniform scalar access:
//   Wt[j][8]    = { b1a[j], W1a[0..5][j], 0 }   (layer-1 t weights, all slices)
//   WpT[j][4]   = { W2a[32..34][j], 0 }         (layer-2 dst-term)
//   W1bS[s][j][8] = W1b[j][s*8 .. s*8+8)        (slice-packed output weights)
//   W2bS[s][j][8] = W2b[j][s*8 .. s*8+8)
__global__ __launch_bounds__(64) void k_packw(const float* __restrict__ W1a,
                                              const float* __restrict__ b1a,
                                              const float* __restrict__ W1b,
                                              const float* __restrict__ W2a,
                                              const float* __restrict__ W2b,
                                              float* __restrict__ Wt,
                                              float* __restrict__ WpT,
                                              float* __restrict__ W1bS,
                                              float* __restrict__ W2bS) {
    int j = threadIdx.x;
    if (j >= H) return;
    Wt[8 * j] = b1a[j];
#pragma unroll
    for (int i = 0; i < 6; i++) Wt[8 * j + 1 + i] = W1a[i * H + j];
    Wt[8 * j + 7] = 0.f;
#pragma unroll
    for (int i = 0; i < 3; i++) WpT[4 * j + i] = W2a[(32 + i) * H + j];
    WpT[4 * j + 3] = 0.f;
    for (int s = 0; s < 4; s++)
#pragma unroll
        for (int k = 0; k < 8; k++) {
            W1bS[(s << 8) + (j << 3) + k] = W1b[j * H + (s << 3) + k];
            W2bS[(s << 8) + (j << 3) + k] = W2b[j * H + (s << 3) + k];
        }
}

__global__ __launch_bounds__(256) void k_hist(const int* __restrict__ dst,
                                              unsigned* __restrict__ hist) {
    int e = blockIdx.x * 256 + threadIdx.x;   // grid covers exactly NE
    atomicAdd(&hist[dst[e]], 1u);
}

// Block-level exclusive scan (Hillis-Steele in LDS), 256 elems/block.
__global__ __launch_bounds__(256) void k_scan1(const unsigned* __restrict__ hist,
                                               unsigned* __restrict__ pre,
                                               unsigned* __restrict__ bsum) {
    __shared__ unsigned sd[256];
    int tid = threadIdx.x;
    int i = blockIdx.x * 256 + tid;
    unsigned v = (i < NN) ? hist[i] : 0u;
    sd[tid] = v;
    __syncthreads();
    for (int off = 1; off < 256; off <<= 1) {
        unsigned t = (tid >= off) ? sd[tid - off] : 0u;
        __syncthreads();
        sd[tid] += t;
        __syncthreads();
    }
    if (i < NN) pre[i] = sd[tid] - v;
    if (tid == 255) bsum[blockIdx.x] = sd[255];
}

__global__ __launch_bounds__(512) void k_scan2(const unsigned* __restrict__ bsum,
                                               unsigned* __restrict__ bpre) {
    __shared__ unsigned sd[512];
    int t = threadIdx.x;
    unsigned v = (t < SB) ? bsum[t] : 0u;
    sd[t] = v;
    __syncthreads();
    for (int off = 1; off < 512; off <<= 1) {
        unsigned x = (t >= off) ? sd[t - off] : 0u;
        __syncthreads();
        sd[t] += x;
        __syncthreads();
    }
    if (t < SB) bpre[t] = sd[t] - v;
}

// cursors[i] = global exclusive prefix (scatter cursor); ends[i] = prefix+count.
__global__ __launch_bounds__(256) void k_scan3(const unsigned* __restrict__ pre,
                                               const unsigned* __restrict__ bpre,
                                               const unsigned* __restrict__ hist,
                                               unsigned* __restrict__ cursors,
                                               unsigned* __restrict__ ends) {
    int i = blockIdx.x * 256 + threadIdx.x;
    if (i < NN) {
        unsigned o = pre[i] + bpre[blockIdx.x];
        cursors[i] = o;
        ends[i] = o + hist[i];
    }
}

// Scatter src ids into dst-sorted order (order within a run is nondeterministic
// but max-reduction is order-free).
__global__ __launch_bounds__(256) void k_scatter(const int* __restrict__ src,
                                                 const int* __restrict__ dst,
                                                 unsigned* __restrict__ cursors,
                                                 unsigned* __restrict__ srcS) {
    int e = blockIdx.x * 256 + threadIdx.x;   // grid covers exactly NE
    int d = dst[e];
    unsigned slot = atomicAdd(&cursors[d], 1u);
    srcS[slot] = (unsigned)src[e];
}

// chunk_node[c] = dst node owning edge c*CE = smallest n with ends[n] > c*CE.
__global__ __launch_bounds__(256) void k_chunks(const unsigned* __restrict__ ends,
                                                unsigned* __restrict__ chunk_node) {
    int c = blockIdx.x * 256 + threadIdx.x;
    if (c >= NCH) return;
    unsigned target = (unsigned)c * CE;
    int lo = 0, hi = NN - 1;
    while (lo < hi) {
        int mid = (lo + hi) >> 1;
        if (ends[mid] <= target) lo = mid + 1; else hi = mid;
    }
    chunk_node[c] = (unsigned)lo;
}

// Layer-1 edge kernel, output-sliced: each chunk is processed by 4 waves of the
// same block; wave w computes channels [w*8, w*8+8). lane -> chunk, wave -> slice.
// slice forced to SGPR (readfirstlane) so all weight addresses are wave-uniform
// -> scalar loads. Per-thread live set ~28 VGPR: nothing to spill.
__global__ __launch_bounds__(256)
void k_edge1(const unsigned* __restrict__ srcS,
             const unsigned* __restrict__ ends,
             const unsigned* __restrict__ chunk_node,
             const float* __restrict__ pos,
             const float* __restrict__ Wt,
             const float* __restrict__ W1bS,
             const float* __restrict__ b1b,
             unsigned* __restrict__ agg) {
    int lane  = threadIdx.x & 63;
    int slice = __builtin_amdgcn_readfirstlane(threadIdx.x >> 6);
    int chunk = blockIdx.x * 64 + lane;            // grid covers NCH exactly
    unsigned base = (unsigned)chunk * CE;
    const float* WbS = W1bS + (slice << 8);
    const float* bb  = b1b + (slice << 3);
    int cur = (int)chunk_node[chunk];
    unsigned end_cur = ends[cur];
    float pd0 = pos[3 * cur], pd1 = pos[3 * cur + 1], pd2 = pos[3 * cur + 2];
    float macc[8];
#pragma unroll
    for (int k = 0; k < 8; k++) macc[k] = 0.f;
#pragma unroll 1
    for (int c = 0; c < CE; c++) {
        unsigned e = base + c;
        if (e >= end_cur) {
            flush8(agg, cur, slice, macc);
            do { cur++; end_cur = ends[cur]; } while (e >= end_cur);
            pd0 = pos[3 * cur]; pd1 = pos[3 * cur + 1]; pd2 = pos[3 * cur + 2];
#pragma unroll
            for (int k = 0; k < 8; k++) macc[k] = 0.f;
        }
        int s = (int)srcS[e];
        float ps0 = pos[3 * s], ps1 = pos[3 * s + 1], ps2 = pos[3 * s + 2];
        float e0 = ps0 - pd0, e1 = ps1 - pd1, e2 = ps2 - pd2;
        float m[8];
#pragma unroll
        for (int k = 0; k < 8; k++) m[k] = bb[k];
#pragma unroll 4
        for (int j = 0; j < H; j++) {
            const float* wr = Wt + (j << 3);
            float t = wr[0];
            t = fmaf(ps0, wr[1], t); t = fmaf(ps1, wr[2], t); t = fmaf(ps2, wr[3], t);
            t = fmaf(e0, wr[4], t);  t = fmaf(e1, wr[5], t);  t = fmaf(e2, wr[6], t);
            t = fmaxf(t, 0.f);
            const float* br = WbS + (j << 3);
#pragma unroll
            for (int k = 0; k < 8; k++) m[k] = fmaf(t, br[k], m[k]);
        }
#pragma unroll
        for (int k = 0; k < 8; k++) macc[k] = fmaxf(macc[k], m[k]);
    }
    flush8(agg, cur, slice, macc);
}

// Layer-2 node precompute: E2[n] = b2a + h[n]@W2a[0:32] + pos[n]@W2a[32:35];
// also resets agg row for reuse by layer 2 (each thread owns its row).
__global__ __launch_bounds__(256) void k_pre2(const float* __restrict__ pos,
                                              unsigned* __restrict__ agg,
                                              const float* __restrict__ W2a,
                                              const float* __restrict__ b2a,
                                              float* __restrict__ E2) {
    int n = blockIdx.x * 256 + threadIdx.x;
    if (n >= NN) return;
    float h[H];
    uint4* A4 = (uint4*)(agg + (size_t)n * H);
#pragma unroll
    for (int r = 0; r < 8; r++) {
        uint4 u = A4[r];
        h[4 * r + 0] = decf(u.x);
        h[4 * r + 1] = decf(u.y);
        h[4 * r + 2] = decf(u.z);
        h[4 * r + 3] = decf(u.w);
        A4[r] = make_uint4(0x80000000u, 0x80000000u, 0x80000000u, 0x80000000u);
    }
    float p0 = pos[3 * n], p1 = pos[3 * n + 1], p2 = pos[3 * n + 2];
    float ev[H];
#pragma unroll
    for (int k = 0; k < H; k++) {
        float v = b2a[k];
        v = fmaf(p0, W2a[32 * H + k], v);
        v = fmaf(p1, W2a[33 * H + k], v);
        v = fmaf(p2, W2a[34 * H + k], v);
        ev[k] = v;
    }
#pragma unroll
    for (int j = 0; j < H; j++) {
        float hj = h[j];
#pragma unroll
        for (int k = 0; k < H; k++) ev[k] = fmaf(hj, W2a[j * H + k], ev[k]);
    }
    float4* E4 = (float4*)(E2 + (size_t)n * H);
#pragma unroll
    for (int r = 0; r < 8; r++)
        E4[r] = make_float4(ev[4 * r], ev[4 * r + 1], ev[4 * r + 2], ev[4 * r + 3]);
}

// Layer-2 edge kernel, output-sliced like k_edge1. The E2 row is consumed in
// four 8-float chunks so only 8 row values are live at a time (per-thread live
// ~35 VGPR). 4 waves read the same rows -> L1/L2 hits after the first.
__global__ __launch_bounds__(256)
void k_edge2(const unsigned* __restrict__ srcS,
             const unsigned* __restrict__ ends,
             const unsigned* __restrict__ chunk_node,
             const float* __restrict__ pos,
             const float* __restrict__ E2,
             const float* __restrict__ WpT,
             const float* __restrict__ W2bS,
             const float* __restrict__ b2b,
             unsigned* __restrict__ agg) {
    int lane  = threadIdx.x & 63;
    int slice = __builtin_amdgcn_readfirstlane(threadIdx.x >> 6);
    int chunk = blockIdx.x * 64 + lane;
    unsigned base = (unsigned)chunk * CE;
    const float* WbS = W2bS + (slice << 8);
    const float* bb  = b2b + (slice << 3);
    int cur = (int)chunk_node[chunk];
    unsigned end_cur = ends[cur];
    float pd0 = pos[3 * cur], pd1 = pos[3 * cur + 1], pd2 = pos[3 * cur + 2];
    float macc[8];
#pragma unroll
    for (int k = 0; k < 8; k++) macc[k] = 0.f;
#pragma unroll 1
    for (int c = 0; c < CE; c++) {
        unsigned e = base + c;
        if (e >= end_cur) {
            flush8(agg, cur, slice, macc);
            do { cur++; end_cur = ends[cur]; } while (e >= end_cur);
            pd0 = pos[3 * cur]; pd1 = pos[3 * cur + 1]; pd2 = pos[3 * cur + 2];
#pragma unroll
            for (int k = 0; k < 8; k++) macc[k] = 0.f;
        }
        int s = (int)srcS[e];
        const float* row = E2 + (size_t)s * H;
        float m[8];
#pragma unroll
        for (int k = 0; k < 8; k++) m[k] = bb[k];
#pragma unroll 1
        for (int cc = 0; cc < 4; cc++) {
            float4 r0 = ((const float4*)(row + (cc << 3)))[0];
            float4 r1 = ((const float4*)(row + (cc << 3)))[1];
            float rv[8] = {r0.x, r0.y, r0.z, r0.w, r1.x, r1.y, r1.z, r1.w};
#pragma unroll
            for (int jj = 0; jj < 8; jj++) {
                int j = (cc << 3) + jj;
                const float* wp = WpT + (j << 2);
                float w = fmaf(pd0, wp[0], fmaf(pd1, wp[1], pd2 * wp[2]));
                float t = fmaxf(rv[jj] - w, 0.f);
                const float* br = WbS + (j << 3);
#pragma unroll
                for (int k = 0; k < 8; k++) m[k] = fmaf(t, br[k], m[k]);
            }
        }
#pragma unroll
        for (int k = 0; k < 8; k++) macc[k] = fmaxf(macc[k], m[k]);
    }
    flush8(agg, cur, slice, macc);
}

// Graph max-pool (encoded domain; max commutes with monotone encoding).
__global__ __launch_bounds__(256) void k_pool(const unsigned* __restrict__ agg,
                                              const int* __restrict__ batch,
                                              unsigned* __restrict__ g) {
    int n = blockIdx.x * 256 + threadIdx.x;
    if (n >= NN) return;
    int bidx = batch[n];
    unsigned* gb = g + (size_t)bidx * H;
    const uint4* A4 = (const uint4*)(agg + (size_t)n * H);
#pragma unroll
    for (int r = 0; r < 8; r++) {
        uint4 v = A4[r];
        uint4 c = ((const uint4*)gb)[r];
        if (v.x > c.x) atomicMax(gb + 4 * r + 0, v.x);
        if (v.y > c.y) atomicMax(gb + 4 * r + 1, v.y);
        if (v.z > c.z) atomicMax(gb + 4 * r + 2, v.z);
        if (v.w > c.w) atomicMax(gb + 4 * r + 3, v.w);
    }
}

__global__ __launch_bounds__(256) void k_out(const unsigned* __restrict__ g,
                                             const float* __restrict__ Wout,
                                             const float* __restrict__ bout,
                                             float* __restrict__ out) {
    int bidx = threadIdx.x;  // one block of 256
    float acc = bout[0];
#pragma unroll
    for (int k = 0; k < H; k++) acc = fmaf(decf(g[bidx * H + k]), Wout[k], acc);
    out[bidx] = acc;
}

extern "C" void kernel_launch(void* const* d_in, const int* in_sizes, int n_in,
                              void* d_out, int out_size, void* d_ws, size_t ws_size,
                              hipStream_t stream) {
    const float* pos  = (const float*)d_in[0];
    const int* src    = (const int*)d_in[1];
    const int* dst    = src + NE;
    const int* batch  = (const int*)d_in[2];
    const float* W1a  = (const float*)d_in[3];
    const float* b1a  = (const float*)d_in[4];
    const float* W1b  = (const float*)d_in[5];
    const float* b1b  = (const float*)d_in[6];
    const float* W2a  = (const float*)d_in[7];
    const float* b2a  = (const float*)d_in[8];
    const float* W2b  = (const float*)d_in[9];
    const float* b2b  = (const float*)d_in[10];
    const float* Wout = (const float*)d_in[11];
    const float* bout = (const float*)d_in[12];
    float* out = (float*)d_out;

    const size_t SZ = (size_t)NN * H;  // 3.2M words
    unsigned* agg        = (unsigned*)d_ws;          // 12.8 MB
    float*    E2         = (float*)d_ws + SZ;        // 12.8 MB (aliased pre-edge1)
    unsigned* srcS       = (unsigned*)d_ws + 2 * SZ; // 12.8 MB (dst-sorted src ids)
    unsigned* g          = (unsigned*)d_ws + 3 * SZ; // 32 KB
    unsigned* ends       = g + NG * H;               // 400 KB (CSR run ends)
    unsigned* chunk_node = ends + NN;                // 1.6 MB (first dst per chunk)
    unsigned* bsum       = chunk_node + NCH;         // scan partials
    unsigned* bpre       = bsum + SB + 1;
    float*    Wt         = (float*)(bpre + SB + 1);  // 256 f: packed t-weights
    float*    WpT        = Wt + 8 * H;               // 128 f: packed dst-term
    float*    W1bS       = WpT + 4 * H;              // 1024 f: slice-packed W1b
    float*    W2bS       = W1bS + 4 * 256;           // 1024 f: slice-packed W2b
    // Sort-phase temporaries aliased into E2's space (dead before k_pre2 writes):
    unsigned* hist    = (unsigned*)E2;
    unsigned* pre     = hist + NN;
    unsigned* cursors = pre + NN;

    const int EDGE_BLOCKS  = NE / 256;          // 12500
    const int INIT_BLOCKS  = (NN * H) / 256;    // 12500
    const int NODE_BLOCKS  = SB;                // 391
    const int CHUNK_BLOCKS = (NCH + 255) / 256; // 1563 (k_chunks)
    const int SLICE_BLOCKS = NCH / 64;          // 6250 (edge kernels, exact)

    k_init<<<INIT_BLOCKS, 256, 0, stream>>>(agg, g, hist);
    k_packw<<<1, 64, 0, stream>>>(W1a, b1a, W1b, W2a, W2b, Wt, WpT, W1bS, W2bS);
    k_hist<<<EDGE_BLOCKS, 256, 0, stream>>>(dst, hist);
    k_scan1<<<NODE_BLOCKS, 256, 0, stream>>>(hist, pre, bsum);
    k_scan2<<<1, 512, 0, stream>>>(bsum, bpre);
    k_scan3<<<NODE_BLOCKS, 256, 0, stream>>>(pre, bpre, hist, cursors, ends);
    k_scatter<<<EDGE_BLOCKS, 256, 0, stream>>>(src, dst, cursors, srcS);
    k_chunks<<<CHUNK_BLOCKS, 256, 0, stream>>>(ends, chunk_node);
    k_edge1<<<SLICE_BLOCKS, 256, 0, stream>>>(srcS, ends, chunk_node, pos,
                                              Wt, W1bS, b1b, agg);
    k_pre2<<<NODE_BLOCKS, 256, 0, stream>>>(pos, agg, W2a, b2a, E2);
    k_edge2<<<SLICE_BLOCKS, 256, 0, stream>>>(srcS, ends, chunk_node, pos, E2,
                                              WpT, W2bS, b2b, agg);
    k_pool<<<NODE_BLOCKS, 256, 0, stream>>>(agg, batch, g);
    k_out<<<1, 256, 0, stream>>>(g, Wout, bout, out);
}

// Round 10
// 1250.238 us; speedup vs baseline: 1.5872x; 1.5872x over previous
//
#include <hip/hip_runtime.h>

#define NN 100000
#define NE 3200000
#define NG 256
#define H 32
#define SB ((NN + 255) / 256)    // 391 scan blocks

// init g=0 (pool accumulator; all pooled values >=0 so raw-bit u32 max works),
// hist=0. Grid 391x256 covers NN.
__global__ __launch_bounds__(256) void k_init(unsigned* __restrict__ g,
                                              unsigned* __restrict__ hist) {
    int i = blockIdx.x * 256 + threadIdx.x;
    if (i < NG * H) g[i] = 0u;
    if (i < NN) hist[i] = 0u;
}

__global__ __launch_bounds__(256) void k_hist(const int* __restrict__ dst,
                                              unsigned* __restrict__ hist) {
    int e = blockIdx.x * 256 + threadIdx.x;   // grid covers exactly NE
    atomicAdd(&hist[dst[e]], 1u);
}

// Block-level exclusive scan (Hillis-Steele in LDS), 256 elems/block.
__global__ __launch_bounds__(256) void k_scan1(const unsigned* __restrict__ hist,
                                               unsigned* __restrict__ pre,
                                               unsigned* __restrict__ bsum) {
    __shared__ unsigned sd[256];
    int tid = threadIdx.x;
    int i = blockIdx.x * 256 + tid;
    unsigned v = (i < NN) ? hist[i] : 0u;
    sd[tid] = v;
    __syncthreads();
    for (int off = 1; off < 256; off <<= 1) {
        unsigned t = (tid >= off) ? sd[tid - off] : 0u;
        __syncthreads();
        sd[tid] += t;
        __syncthreads();
    }
    if (i < NN) pre[i] = sd[tid] - v;
    if (tid == 255) bsum[blockIdx.x] = sd[255];
}

__global__ __launch_bounds__(512) void k_scan2(const unsigned* __restrict__ bsum,
                                               unsigned* __restrict__ bpre) {
    __shared__ unsigned sd[512];
    int t = threadIdx.x;
    unsigned v = (t < SB) ? bsum[t] : 0u;
    sd[t] = v;
    __syncthreads();
    for (int off = 1; off < 512; off <<= 1) {
        unsigned x = (t >= off) ? sd[t - off] : 0u;
        __syncthreads();
        sd[t] += x;
        __syncthreads();
    }
    if (t < SB) bpre[t] = sd[t] - v;
}

// cursors[i] = global exclusive prefix (scatter cursor); ends[i] = prefix+count.
__global__ __launch_bounds__(256) void k_scan3(const unsigned* __restrict__ pre,
                                               const unsigned* __restrict__ bpre,
                                               const unsigned* __restrict__ hist,
                                               unsigned* __restrict__ cursors,
                                               unsigned* __restrict__ ends) {
    int i = blockIdx.x * 256 + threadIdx.x;
    if (i < NN) {
        unsigned o = pre[i] + bpre[blockIdx.x];
        cursors[i] = o;
        ends[i] = o + hist[i];
    }
}

// Scatter src ids into dst-sorted order (order within a run is nondeterministic
// but max-reduction is order-free).
__global__ __launch_bounds__(256) void k_scatter(const int* __restrict__ src,
                                                 const int* __restrict__ dst,
                                                 unsigned* __restrict__ cursors,
                                                 unsigned* __restrict__ srcS) {
    int e = blockIdx.x * 256 + threadIdx.x;   // grid covers exactly NE
    int d = dst[e];
    unsigned slot = atomicAdd(&cursors[d], 1u);
    srcS[slot] = (unsigned)src[e];
}

// Layer-1 src-side precompute:
//   E1[n][k] = b1a[k] + sum_i pos[n][i]*(W1a[i][k] + W1a[3+i][k])
// so per-edge t_k = relu(E1[src][k] - fd_k(dst)), fd_k = pos[dst]@W1a[3:6][k].
__global__ __launch_bounds__(256) void k_pre1(const float* __restrict__ pos,
                                              const float* __restrict__ W1a,
                                              const float* __restrict__ b1a,
                                              float* __restrict__ E) {
    int n = blockIdx.x * 256 + threadIdx.x;
    if (n >= NN) return;
    float p0 = pos[3 * n], p1 = pos[3 * n + 1], p2 = pos[3 * n + 2];
    float ev[H];
#pragma unroll
    for (int k = 0; k < H; k++) {
        float v = b1a[k];
        v = fmaf(p0, W1a[k] + W1a[96 + k], v);
        v = fmaf(p1, W1a[32 + k] + W1a[128 + k], v);
        v = fmaf(p2, W1a[64 + k] + W1a[160 + k], v);
        ev[k] = v;
    }
    float4* E4 = (float4*)(E + (size_t)n * H);
#pragma unroll
    for (int r = 0; r < 8; r++)
        E4[r] = make_float4(ev[4 * r], ev[4 * r + 1], ev[4 * r + 2], ev[4 * r + 3]);
}

// Layer-2 src-side precompute: E2[n][k] = b2a[k] + h1[n]@W2a[0:32][k]
//   + pos[n]@W2a[32:35][k]   (h1 = agg from layer 1, plain float, >=0)
__global__ __launch_bounds__(256) void k_pre2(const float* __restrict__ pos,
                                              const float* __restrict__ agg,
                                              const float* __restrict__ W2a,
                                              const float* __restrict__ b2a,
                                              float* __restrict__ E) {
    int n = blockIdx.x * 256 + threadIdx.x;
    if (n >= NN) return;
    float h[H];
    const float4* A4 = (const float4*)(agg + (size_t)n * H);
#pragma unroll
    for (int r = 0; r < 8; r++) {
        float4 u = A4[r];
        h[4 * r + 0] = u.x; h[4 * r + 1] = u.y;
        h[4 * r + 2] = u.z; h[4 * r + 3] = u.w;
    }
    float p0 = pos[3 * n], p1 = pos[3 * n + 1], p2 = pos[3 * n + 2];
    float ev[H];
#pragma unroll
    for (int k = 0; k < H; k++) {
        float v = b2a[k];
        v = fmaf(p0, W2a[32 * H + k], v);
        v = fmaf(p1, W2a[33 * H + k], v);
        v = fmaf(p2, W2a[34 * H + k], v);
        ev[k] = v;
    }
#pragma unroll
    for (int j = 0; j < H; j++) {
        float hj = h[j];
#pragma unroll
        for (int k = 0; k < H; k++) ev[k] = fmaf(hj, W2a[j * H + k], ev[k]);
    }
    float4* E4 = (float4*)(E + (size_t)n * H);
#pragma unroll
    for (int r = 0; r < 8; r++)
        E4[r] = make_float4(ev[4 * r], ev[4 * r + 1], ev[4 * r + 2], ev[4 * r + 3]);
}

// Unified edge kernel: ONE WAVE PER NODE (atomic-free aggregation).
//   lane j owns channel j. Per edge of the node's CSR segment:
//     t_j = relu(E[s][j] - fd_j)       (coalesced 128B row load)
//     msg_k = b[k] + sum_j t_j Wb[j][k] via v_readlane(t, jj) + fmac (no DS)
//     macc_k = max(macc_k, msg_k)      (register; init 0 folds relu + 0-fill)
//   Layer 1: lanes 0-31 store h row (plain 128B store).
//   Layer 2: fused graph max-pool: raw-bit atomicMax on g (values >= 0).
__global__ __launch_bounds__(256) void k_edge(const unsigned* __restrict__ srcS,
                                              const unsigned* __restrict__ ends,
                                              const float* __restrict__ pos,
                                              const float* __restrict__ E,
                                              const float* __restrict__ Wf,
                                              const float* __restrict__ Wb,
                                              const float* __restrict__ bb,
                                              float* __restrict__ aggOut,
                                              const int* __restrict__ batch,
                                              unsigned* __restrict__ g,
                                              int layer2) {
    int lane = threadIdx.x & 63;
    int j = lane & 31;
    int node = __builtin_amdgcn_readfirstlane(blockIdx.x * 4 + (threadIdx.x >> 6));
    unsigned start = (node == 0) ? 0u : ends[node - 1];
    unsigned endv = ends[node];
    int deg = (int)(endv - start);
    // per-channel constants (registers; Wb 4KB is L1-resident across waves)
    float wcol[H];
#pragma unroll
    for (int jj = 0; jj < H; jj++) wcol[jj] = Wb[jj * H + j];
    float bbv = bb[j];
    float pd0 = pos[3 * node], pd1 = pos[3 * node + 1], pd2 = pos[3 * node + 2];
    float fd = fmaf(pd0, Wf[j], fmaf(pd1, Wf[H + j], pd2 * Wf[2 * H + j]));
    float macc = 0.f;
    if (deg > 0) {
        int s = (int)srcS[start];
        float val = E[(size_t)s * H + j];
        for (int i = 0; i < deg; i++) {
            float vnext = 0.f;
            if (i + 1 < deg) {               // prefetch next row (uniform branch)
                int s2 = (int)srcS[start + i + 1];
                vnext = E[(size_t)s2 * H + j];
            }
            float t = fmaxf(val - fd, 0.f);
            float m = bbv;
#pragma unroll
            for (int jj = 0; jj < H; jj++) {
                float tj = __uint_as_float(
                    (unsigned)__builtin_amdgcn_readlane(__float_as_uint(t), jj));
                m = fmaf(tj, wcol[jj], m);
            }
            macc = fmaxf(macc, m);
            val = vnext;
        }
    }
    if (lane < H) {
        if (!layer2) {
            aggOut[(size_t)node * H + lane] = macc;   // h1 (>=0, relu folded)
        } else {
            int b = batch[node];
            unsigned bits = __float_as_uint(macc);    // nonneg: bit order = value order
            unsigned* gb = g + ((size_t)b << 5) + lane;
            if (bits > *gb) atomicMax(gb, bits);
        }
    }
}

__global__ __launch_bounds__(256) void k_out(const unsigned* __restrict__ g,
                                             const float* __restrict__ Wout,
                                             const float* __restrict__ bout,
                                             float* __restrict__ out) {
    int bidx = threadIdx.x;  // one block of 256
    float acc = bout[0];
#pragma unroll
    for (int k = 0; k < H; k++)
        acc = fmaf(__uint_as_float(g[bidx * H + k]), Wout[k], acc);
    out[bidx] = acc;
}

extern "C" void kernel_launch(void* const* d_in, const int* in_sizes, int n_in,
                              void* d_out, int out_size, void* d_ws, size_t ws_size,
                              hipStream_t stream) {
    const float* pos  = (const float*)d_in[0];
    const int* src    = (const int*)d_in[1];
    const int* dst    = src + NE;
    const int* batch  = (const int*)d_in[2];
    const float* W1a  = (const float*)d_in[3];
    const float* b1a  = (const float*)d_in[4];
    const float* W1b  = (const float*)d_in[5];
    const float* b1b  = (const float*)d_in[6];
    const float* W2a  = (const float*)d_in[7];
    const float* b2a  = (const float*)d_in[8];
    const float* W2b  = (const float*)d_in[9];
    const float* b2b  = (const float*)d_in[10];
    const float* Wout = (const float*)d_in[11];
    const float* bout = (const float*)d_in[12];
    float* out = (float*)d_out;

    const size_t SZ = (size_t)NN * H;  // 3.2M words
    float*    agg  = (float*)d_ws;                   // 12.8 MB (h1)
    float*    E    = (float*)d_ws + SZ;              // 12.8 MB (E1 then E2)
    unsigned* srcS = (unsigned*)d_ws + 2 * SZ;       // 12.8 MB (dst-sorted src)
    unsigned* g    = (unsigned*)d_ws + 3 * SZ;       // 32 KB (pool)
    unsigned* ends = g + NG * H;                     // 400 KB (CSR ends)
    unsigned* bsum = ends + NN;                      // scan partials
    unsigned* bpre = bsum + SB + 1;
    // Sort-phase temporaries aliased into agg's space (agg first written by
    // k_edge layer-1, which runs after the sort is complete):
    unsigned* hist    = (unsigned*)agg;
    unsigned* pre     = hist + NN;
    unsigned* cursors = pre + NN;

    const int EDGE_BLOCKS = NE / 256;   // 12500
    const int NODE_BLOCKS = SB;         // 391
    const int WAVE_BLOCKS = NN / 4;     // 25000 (4 node-waves per block, exact)

    k_init<<<NODE_BLOCKS, 256, 0, stream>>>(g, hist);
    k_hist<<<EDGE_BLOCKS, 256, 0, stream>>>(dst, hist);
    k_scan1<<<NODE_BLOCKS, 256, 0, stream>>>(hist, pre, bsum);
    k_scan2<<<1, 512, 0, stream>>>(bsum, bpre);
    k_scan3<<<NODE_BLOCKS, 256, 0, stream>>>(pre, bpre, hist, cursors, ends);
    k_scatter<<<EDGE_BLOCKS, 256, 0, stream>>>(src, dst, cursors, srcS);
    k_pre1<<<NODE_BLOCKS, 256, 0, stream>>>(pos, W1a, b1a, E);
    k_edge<<<WAVE_BLOCKS, 256, 0, stream>>>(srcS, ends, pos, E,
                                            W1a + 3 * H, W1b, b1b,
                                            agg, batch, g, 0);
    k_pre2<<<NODE_BLOCKS, 256, 0, stream>>>(pos, agg, W2a, b2a, E);
    k_edge<<<WAVE_BLOCKS, 256, 0, stream>>>(srcS, ends, pos, E,
                                            W2a + 32 * H, W2b, b2b,
                                            agg, batch, g, 1);
    k_out<<<1, 256, 0, stream>>>(g, Wout, bout, out);
}

// Round 12
// 977.764 us; speedup vs baseline: 2.0295x; 1.2787x over previous
//
#include <hip/hip_runtime.h>

#define NN 100000
#define NE 3200000
#define NG 256
#define H 32
#define SB ((NN + 255) / 256)    // 391 scan blocks

// init g=0 (pool accumulator; all pooled values >=0 so raw-bit u32 max works),
// hist=0. Grid 391x256 covers NN.
__global__ __launch_bounds__(256) void k_init(unsigned* __restrict__ g,
                                              unsigned* __restrict__ hist) {
    int i = blockIdx.x * 256 + threadIdx.x;
    if (i < NG * H) g[i] = 0u;
    if (i < NN) hist[i] = 0u;
}

__global__ __launch_bounds__(256) void k_hist(const int* __restrict__ dst,
                                              unsigned* __restrict__ hist) {
    int e = blockIdx.x * 256 + threadIdx.x;   // grid covers exactly NE
    atomicAdd(&hist[dst[e]], 1u);
}

// Block-level exclusive scan (Hillis-Steele in LDS), 256 elems/block.
__global__ __launch_bounds__(256) void k_scan1(const unsigned* __restrict__ hist,
                                               unsigned* __restrict__ pre,
                                               unsigned* __restrict__ bsum) {
    __shared__ unsigned sd[256];
    int tid = threadIdx.x;
    int i = blockIdx.x * 256 + tid;
    unsigned v = (i < NN) ? hist[i] : 0u;
    sd[tid] = v;
    __syncthreads();
    for (int off = 1; off < 256; off <<= 1) {
        unsigned t = (tid >= off) ? sd[tid - off] : 0u;
        __syncthreads();
        sd[tid] += t;
        __syncthreads();
    }
    if (i < NN) pre[i] = sd[tid] - v;
    if (tid == 255) bsum[blockIdx.x] = sd[255];
}

__global__ __launch_bounds__(512) void k_scan2(const unsigned* __restrict__ bsum,
                                               unsigned* __restrict__ bpre) {
    __shared__ unsigned sd[512];
    int t = threadIdx.x;
    unsigned v = (t < SB) ? bsum[t] : 0u;
    sd[t] = v;
    __syncthreads();
    for (int off = 1; off < 512; off <<= 1) {
        unsigned x = (t >= off) ? sd[t - off] : 0u;
        __syncthreads();
        sd[t] += x;
        __syncthreads();
    }
    if (t < SB) bpre[t] = sd[t] - v;
}

// cursors[i] = global exclusive prefix (scatter cursor); ends[i] = prefix+count.
__global__ __launch_bounds__(256) void k_scan3(const unsigned* __restrict__ pre,
                                               const unsigned* __restrict__ bpre,
                                               const unsigned* __restrict__ hist,
                                               unsigned* __restrict__ cursors,
                                               unsigned* __restrict__ ends) {
    int i = blockIdx.x * 256 + threadIdx.x;
    if (i < NN) {
        unsigned o = pre[i] + bpre[blockIdx.x];
        cursors[i] = o;
        ends[i] = o + hist[i];
    }
}

// Scatter src ids into dst-sorted order (order within a run is nondeterministic
// but max-reduction is order-free).
__global__ __launch_bounds__(256) void k_scatter(const int* __restrict__ src,
                                                 const int* __restrict__ dst,
                                                 unsigned* __restrict__ cursors,
                                                 unsigned* __restrict__ srcS) {
    int e = blockIdx.x * 256 + threadIdx.x;   // grid covers exactly NE
    int d = dst[e];
    unsigned slot = atomicAdd(&cursors[d], 1u);
    srcS[slot] = (unsigned)src[e];
}

// Layer-1 src-side precompute:
//   E1[n][k] = b1a[k] + sum_i pos[n][i]*(W1a[i][k] + W1a[3+i][k])
// so per-edge t_k = relu(E1[src][k] - fd_k(dst)), fd_k = pos[dst]@W1a[3:6][k].
__global__ __launch_bounds__(256) void k_pre1(const float* __restrict__ pos,
                                              const float* __restrict__ W1a,
                                              const float* __restrict__ b1a,
                                              float* __restrict__ E) {
    int n = blockIdx.x * 256 + threadIdx.x;
    if (n >= NN) return;
    float p0 = pos[3 * n], p1 = pos[3 * n + 1], p2 = pos[3 * n + 2];
    float ev[H];
#pragma unroll
    for (int k = 0; k < H; k++) {
        float v = b1a[k];
        v = fmaf(p0, W1a[k] + W1a[96 + k], v);
        v = fmaf(p1, W1a[32 + k] + W1a[128 + k], v);
        v = fmaf(p2, W1a[64 + k] + W1a[160 + k], v);
        ev[k] = v;
    }
    float4* E4 = (float4*)(E + (size_t)n * H);
#pragma unroll
    for (int r = 0; r < 8; r++)
        E4[r] = make_float4(ev[4 * r], ev[4 * r + 1], ev[4 * r + 2], ev[4 * r + 3]);
}

// Layer-2 src-side precompute: E2[n][k] = b2a[k] + h1[n]@W2a[0:32][k]
//   + pos[n]@W2a[32:35][k]   (h1 = agg from layer 1, plain float, >=0)
__global__ __launch_bounds__(256) void k_pre2(const float* __restrict__ pos,
                                              const float* __restrict__ agg,
                                              const float* __restrict__ W2a,
                                              const float* __restrict__ b2a,
                                              float* __restrict__ E) {
    int n = blockIdx.x * 256 + threadIdx.x;
    if (n >= NN) return;
    float h[H];
    const float4* A4 = (const float4*)(agg + (size_t)n * H);
#pragma unroll
    for (int r = 0; r < 8; r++) {
        float4 u = A4[r];
        h[4 * r + 0] = u.x; h[4 * r + 1] = u.y;
        h[4 * r + 2] = u.z; h[4 * r + 3] = u.w;
    }
    float p0 = pos[3 * n], p1 = pos[3 * n + 1], p2 = pos[3 * n + 2];
    float ev[H];
#pragma unroll
    for (int k = 0; k < H; k++) {
        float v = b2a[k];
        v = fmaf(p0, W2a[32 * H + k], v);
        v = fmaf(p1, W2a[33 * H + k], v);
        v = fmaf(p2, W2a[34 * H + k], v);
        ev[k] = v;
    }
#pragma unroll
    for (int j = 0; j < H; j++) {
        float hj = h[j];
#pragma unroll
        for (int k = 0; k < H; k++) ev[k] = fmaf(hj, W2a[j * H + k], ev[k]);
    }
    float4* E4 = (float4*)(E + (size_t)n * H);
#pragma unroll
    for (int r = 0; r < 8; r++)
        E4[r] = make_float4(ev[4 * r], ev[4 * r + 1], ev[4 * r + 2], ev[4 * r + 3]);
}

// ds_swizzle BitMode broadcast: every lane reads lane (or_mask) within its
// 32-lane group. offset = (0<<10)|(jj<<5)|0 -> and=0, or=jj, xor=0.
#define SWZ(t, imm) __uint_as_float((unsigned)__builtin_amdgcn_ds_swizzle( \
        (int)__float_as_uint(t), (imm)))
#define PAIR(jj) { \
        float ta = SWZ(t, ((jj) << 5)); \
        float tb = SWZ(t, (((jj) + 1) << 5)); \
        m0 = fmaf(ta, wcol[(jj)], m0); \
        m1 = fmaf(tb, wcol[(jj) + 1], m1); }

// Unified edge kernel: ONE WAVE PER NODE, TWO EDGES PER ITERATION.
//   lane = (eh = lane>>5: which edge of the pair, j = lane&31: channel).
//   t_j = relu(E[s(eh)][j] - fd_j): one coalesced 256B load covers both rows.
//   Broadcast t_jj within each 32-lane half via ds_swizzle (DS pipe, overlaps
//   the FMA chain on VALU). Odd degree: both halves process the last edge
//   (duplicate is a no-op for max). Aggregation entirely in registers; single
//   coalesced store (layer 1) or raw-bit atomicMax into 32KB pool (layer 2).
__global__ __launch_bounds__(256) void k_edge(const unsigned* __restrict__ srcS,
                                              const unsigned* __restrict__ ends,
                                              const float* __restrict__ pos,
                                              const float* __restrict__ E,
                                              const float* __restrict__ Wf,
                                              const float* __restrict__ Wb,
                                              const float* __restrict__ bb,
                                              float* __restrict__ aggOut,
                                              const int* __restrict__ batch,
                                              unsigned* __restrict__ g,
                                              int layer2) {
    int lane = threadIdx.x & 63;
    int j = lane & 31;
    int eh = lane >> 5;
    int node = __builtin_amdgcn_readfirstlane(blockIdx.x * 4 + (threadIdx.x >> 6));
    unsigned start = (node == 0) ? 0u : ends[node - 1];
    int deg = (int)(ends[node] - start);
    // per-channel constants; Wb (4KB) is L1-resident across all waves
    float wcol[H];
#pragma unroll
    for (int jj = 0; jj < H; jj++) wcol[jj] = Wb[jj * H + j];
    float bbv = bb[j];
    float pd0 = pos[3 * node], pd1 = pos[3 * node + 1], pd2 = pos[3 * node + 2];
    float fd = fmaf(pd0, Wf[j], fmaf(pd1, Wf[H + j], pd2 * Wf[2 * H + j]));
    float macc = 0.f;
    if (deg > 0) {
        int last = deg - 1;
        int i0 = (eh <= last) ? eh : last;
        int s = (int)srcS[start + i0];
        float val = E[(size_t)s * H + j];
        for (int i = 0; i < deg; i += 2) {
            float vnext = 0.f;
            if (i + 2 < deg) {                 // prefetch next pair's row element
                int nx = i + 2 + eh; if (nx > last) nx = last;
                int s2 = (int)srcS[start + nx];
                vnext = E[(size_t)s2 * H + j];
            }
            float t = fmaxf(val - fd, 0.f);
            float m0 = bbv, m1 = 0.f;          // split chain: 2 accumulators
            PAIR(0)  PAIR(2)  PAIR(4)  PAIR(6)
            PAIR(8)  PAIR(10) PAIR(12) PAIR(14)
            PAIR(16) PAIR(18) PAIR(20) PAIR(22)
            PAIR(24) PAIR(26) PAIR(28) PAIR(30)
            macc = fmaxf(macc, m0 + m1);
            val = vnext;
        }
    }
    // combine the two edge-halves: lane<32 takes max with lane+32's macc
    float other = __shfl_down(macc, 32);
    if (lane < H) {
        macc = fmaxf(macc, other);
        if (!layer2) {
            aggOut[(size_t)node * H + lane] = macc;   // h1 (>=0, relu folded)
        } else {
            int b = batch[node];
            unsigned bits = __float_as_uint(macc);    // nonneg: bit order = value
            unsigned* gb = g + ((size_t)b << 5) + lane;
            if (bits > *gb) atomicMax(gb, bits);
        }
    }
}

__global__ __launch_bounds__(256) void k_out(const unsigned* __restrict__ g,
                                             const float* __restrict__ Wout,
                                             const float* __restrict__ bout,
                                             float* __restrict__ out) {
    int bidx = threadIdx.x;  // one block of 256
    float acc = bout[0];
#pragma unroll
    for (int k = 0; k < H; k++)
        acc = fmaf(__uint_as_float(g[bidx * H + k]), Wout[k], acc);
    out[bidx] = acc;
}

extern "C" void kernel_launch(void* const* d_in, const int* in_sizes, int n_in,
                              void* d_out, int out_size, void* d_ws, size_t ws_size,
                              hipStream_t stream) {
    const float* pos  = (const float*)d_in[0];
    const int* src    = (const int*)d_in[1];
    const int* dst    = src + NE;
    const int* batch  = (const int*)d_in[2];
    const float* W1a  = (const float*)d_in[3];
    const float* b1a  = (const float*)d_in[4];
    const float* W1b  = (const float*)d_in[5];
    const float* b1b  = (const float*)d_in[6];
    const float* W2a  = (const float*)d_in[7];
    const float* b2a  = (const float*)d_in[8];
    const float* W2b  = (const float*)d_in[9];
    const float* b2b  = (const float*)d_in[10];
    const float* Wout = (const float*)d_in[11];
    const float* bout = (const float*)d_in[12];
    float* out = (float*)d_out;

    const size_t SZ = (size_t)NN * H;  // 3.2M words
    float*    agg  = (float*)d_ws;                   // 12.8 MB (h1)
    float*    E    = (float*)d_ws + SZ;              // 12.8 MB (E1 then E2)
    unsigned* srcS = (unsigned*)d_ws + 2 * SZ;       // 12.8 MB (dst-sorted src)
    unsigned* g    = (unsigned*)d_ws + 3 * SZ;       // 32 KB (pool)
    unsigned* ends = g + NG * H;                     // 400 KB (CSR ends)
    unsigned* bsum = ends + NN;                      // scan partials
    unsigned* bpre = bsum + SB + 1;
    // Sort-phase temporaries aliased into agg's space (agg first written by
    // k_edge layer-1, which runs after the sort is complete):
    unsigned* hist    = (unsigned*)agg;
    unsigned* pre     = hist + NN;
    unsigned* cursors = pre + NN;

    const int EDGE_BLOCKS = NE / 256;   // 12500
    const int NODE_BLOCKS = SB;         // 391
    const int WAVE_BLOCKS = NN / 4;     // 25000 (4 node-waves per block, exact)

    k_init<<<NODE_BLOCKS, 256, 0, stream>>>(g, hist);
    k_hist<<<EDGE_BLOCKS, 256, 0, stream>>>(dst, hist);
    k_scan1<<<NODE_BLOCKS, 256, 0, stream>>>(hist, pre, bsum);
    k_scan2<<<1, 512, 0, stream>>>(bsum, bpre);
    k_scan3<<<NODE_BLOCKS, 256, 0, stream>>>(pre, bpre, hist, cursors, ends);
    k_scatter<<<EDGE_BLOCKS, 256, 0, stream>>>(src, dst, cursors, srcS);
    k_pre1<<<NODE_BLOCKS, 256, 0, stream>>>(pos, W1a, b1a, E);
    k_edge<<<WAVE_BLOCKS, 256, 0, stream>>>(srcS, ends, pos, E,
                                            W1a + 3 * H, W1b, b1b,
                                            agg, batch, g, 0);
    k_pre2<<<NODE_BLOCKS, 256, 0, stream>>>(pos, agg, W2a, b2a, E);
    k_edge<<<WAVE_BLOCKS, 256, 0, stream>>>(srcS, ends, pos, E,
                                            W2a + 32 * H, W2b, b2b,
                                            agg, batch, g, 1);
    k_out<<<1, 256, 0, stream>>>(g, Wout, bout, out);
}

// Round 13
// 758.261 us; speedup vs baseline: 2.6170x; 1.2895x over previous
//
#include <hip/hip_runtime.h>

#define NN 100000
#define NE 3200000
#define NG 256
#define H 32
#define SB ((NN + 255) / 256)    // 391 scan blocks

typedef __attribute__((ext_vector_type(8))) short b16x8;   // 8 bf16 = 4 VGPRs
typedef __attribute__((ext_vector_type(4))) float f32x4;

union ABfrag { unsigned u[4]; b16x8 v; };

// init g=0 (pool accumulator; pooled values >=0 so raw-bit u32 max works),
// hist=0. Grid 391x256 covers NN.
__global__ __launch_bounds__(256) void k_init(unsigned* __restrict__ g,
                                              unsigned* __restrict__ hist) {
    int i = blockIdx.x * 256 + threadIdx.x;
    if (i < NG * H) g[i] = 0u;
    if (i < NN) hist[i] = 0u;
}

// Pack Wb (32x32) of both layers into MFMA B-fragments, bf16 hi/lo split.
// B[k][n] for half h: value W[k*32 + h*16 + n]; lane l holds col n=l&15,
// k = 8*(l>>4)+i (i=0..7, pairs packed low-short-first).
// Wpk dword layout: ((layer*4 + h*2 + hl)*64 + lane)*4 + w   (16 KB total)
__global__ __launch_bounds__(64) void k_packw(const float* __restrict__ W1b,
                                              const float* __restrict__ W2b,
                                              unsigned* __restrict__ Wpk) {
    int l = threadIdx.x;
    int n = l & 15, gq = l >> 4;
    for (int layer = 0; layer < 2; layer++) {
        const float* W = layer ? W2b : W1b;
        for (int h = 0; h < 2; h++) {
            unsigned hi[8], lo[8];
#pragma unroll
            for (int i = 0; i < 8; i++) {
                float w = W[(8 * gq + i) * H + h * 16 + n];
                unsigned wb = __float_as_uint(w);
                unsigned hb = wb & 0xffff0000u;
                float r = w - __uint_as_float(hb);
                hi[i] = hb;
                lo[i] = __float_as_uint(r) & 0xffff0000u;
            }
            unsigned* dh = Wpk + (((layer * 4 + h * 2 + 0) * 64) + l) * 4;
            unsigned* dl = Wpk + (((layer * 4 + h * 2 + 1) * 64) + l) * 4;
#pragma unroll
            for (int w2 = 0; w2 < 4; w2++) {
                dh[w2] = (hi[2 * w2] >> 16) | (hi[2 * w2 + 1] & 0xffff0000u);
                dl[w2] = (lo[2 * w2] >> 16) | (lo[2 * w2 + 1] & 0xffff0000u);
            }
        }
    }
}

__global__ __launch_bounds__(256) void k_hist(const int* __restrict__ dst,
                                              unsigned* __restrict__ hist) {
    int e = blockIdx.x * 256 + threadIdx.x;   // grid covers exactly NE
    atomicAdd(&hist[dst[e]], 1u);
}

// Block-level exclusive scan (Hillis-Steele in LDS), 256 elems/block.
__global__ __launch_bounds__(256) void k_scan1(const unsigned* __restrict__ hist,
                                               unsigned* __restrict__ pre,
                                               unsigned* __restrict__ bsum) {
    __shared__ unsigned sd[256];
    int tid = threadIdx.x;
    int i = blockIdx.x * 256 + tid;
    unsigned v = (i < NN) ? hist[i] : 0u;
    sd[tid] = v;
    __syncthreads();
    for (int off = 1; off < 256; off <<= 1) {
        unsigned t = (tid >= off) ? sd[tid - off] : 0u;
        __syncthreads();
        sd[tid] += t;
        __syncthreads();
    }
    if (i < NN) pre[i] = sd[tid] - v;
    if (tid == 255) bsum[blockIdx.x] = sd[255];
}

__global__ __launch_bounds__(512) void k_scan2(const unsigned* __restrict__ bsum,
                                               unsigned* __restrict__ bpre) {
    __shared__ unsigned sd[512];
    int t = threadIdx.x;
    unsigned v = (t < SB) ? bsum[t] : 0u;
    sd[t] = v;
    __syncthreads();
    for (int off = 1; off < 512; off <<= 1) {
        unsigned x = (t >= off) ? sd[t - off] : 0u;
        __syncthreads();
        sd[t] += x;
        __syncthreads();
    }
    if (t < SB) bpre[t] = sd[t] - v;
}

// cursors[i] = global exclusive prefix (scatter cursor); ends[i] = prefix+count.
__global__ __launch_bounds__(256) void k_scan3(const unsigned* __restrict__ pre,
                                               const unsigned* __restrict__ bpre,
                                               const unsigned* __restrict__ hist,
                                               unsigned* __restrict__ cursors,
                                               unsigned* __restrict__ ends) {
    int i = blockIdx.x * 256 + threadIdx.x;
    if (i < NN) {
        unsigned o = pre[i] + bpre[blockIdx.x];
        cursors[i] = o;
        ends[i] = o + hist[i];
    }
}

// Scatter src ids into dst-sorted order (order within a run is nondeterministic
// but max-reduction is order-free).
__global__ __launch_bounds__(256) void k_scatter(const int* __restrict__ src,
                                                 const int* __restrict__ dst,
                                                 unsigned* __restrict__ cursors,
                                                 unsigned* __restrict__ srcS) {
    int e = blockIdx.x * 256 + threadIdx.x;   // grid covers exactly NE
    int d = dst[e];
    unsigned slot = atomicAdd(&cursors[d], 1u);
    srcS[slot] = (unsigned)src[e];
}

// Layer-1 src-side precompute:
//   E1[n][k] = b1a[k] + sum_i pos[n][i]*(W1a[i][k] + W1a[3+i][k])
// so per-edge t_k = relu(E1[src][k] - fd_k(dst)), fd_k = pos[dst]@W1a[3:6][k].
__global__ __launch_bounds__(256) void k_pre1(const float* __restrict__ pos,
                                              const float* __restrict__ W1a,
                                              const float* __restrict__ b1a,
                                              float* __restrict__ E) {
    int n = blockIdx.x * 256 + threadIdx.x;
    if (n >= NN) return;
    float p0 = pos[3 * n], p1 = pos[3 * n + 1], p2 = pos[3 * n + 2];
    float ev[H];
#pragma unroll
    for (int k = 0; k < H; k++) {
        float v = b1a[k];
        v = fmaf(p0, W1a[k] + W1a[96 + k], v);
        v = fmaf(p1, W1a[32 + k] + W1a[128 + k], v);
        v = fmaf(p2, W1a[64 + k] + W1a[160 + k], v);
        ev[k] = v;
    }
    float4* E4 = (float4*)(E + (size_t)n * H);
#pragma unroll
    for (int r = 0; r < 8; r++)
        E4[r] = make_float4(ev[4 * r], ev[4 * r + 1], ev[4 * r + 2], ev[4 * r + 3]);
}

// Layer-2 src-side precompute: E2[n][k] = b2a[k] + h1[n]@W2a[0:32][k]
//   + pos[n]@W2a[32:35][k]   (h1 = agg from layer 1, plain float, >=0)
__global__ __launch_bounds__(256) void k_pre2(const float* __restrict__ pos,
                                              const float* __restrict__ agg,
                                              const float* __restrict__ W2a,
                                              const float* __restrict__ b2a,
                                              float* __restrict__ E) {
    int n = blockIdx.x * 256 + threadIdx.x;
    if (n >= NN) return;
    float h[H];
    const float4* A4 = (const float4*)(agg + (size_t)n * H);
#pragma unroll
    for (int r = 0; r < 8; r++) {
        float4 u = A4[r];
        h[4 * r + 0] = u.x; h[4 * r + 1] = u.y;
        h[4 * r + 2] = u.z; h[4 * r + 3] = u.w;
    }
    float p0 = pos[3 * n], p1 = pos[3 * n + 1], p2 = pos[3 * n + 2];
    float ev[H];
#pragma unroll
    for (int k = 0; k < H; k++) {
        float v = b2a[k];
        v = fmaf(p0, W2a[32 * H + k], v);
        v = fmaf(p1, W2a[33 * H + k], v);
        v = fmaf(p2, W2a[34 * H + k], v);
        ev[k] = v;
    }
#pragma unroll
    for (int j = 0; j < H; j++) {
        float hj = h[j];
#pragma unroll
        for (int k = 0; k < H; k++) ev[k] = fmaf(hj, W2a[j * H + k], ev[k]);
    }
    float4* E4 = (float4*)(E + (size_t)n * H);
#pragma unroll
    for (int r = 0; r < 8; r++)
        E4[r] = make_float4(ev[4 * r], ev[4 * r + 1], ev[4 * r + 2], ev[4 * r + 3]);
}

// MFMA edge kernel: ONE WAVE PER NODE, 16 EDGES PER TILE.
//   A (16 edges x 32 j): lane = (row = lane&15 -> edge, kblk = lane>>4 ->
//   j0 = 8*kblk). Lane loads its 32B E-row segment, computes
//   t = relu(E - fd) for 8 j's, splits to bf16 hi/lo (v_perm pack).
//   B (32 j x 16 ch-half): pre-packed fragments (hi/lo), 2 halves.
//   D = T@Wb via 3-term split: hi*hi + lo*hi + hi*lo per half.
//   Max over edges: 4 reg v_max per tile + xor16/xor32 reduce once per wave.
//   Tail padding duplicates the last edge (max-idempotent). No DS in the loop,
//   no atomics (layer 1) / few pool atomics (layer 2).
__global__ __launch_bounds__(256) void k_edge(const unsigned* __restrict__ srcS,
                                              const unsigned* __restrict__ ends,
                                              const float* __restrict__ pos,
                                              const float* __restrict__ E,
                                              const float* __restrict__ Wf,
                                              const unsigned* __restrict__ WpkL,
                                              const float* __restrict__ bb,
                                              float* __restrict__ aggOut,
                                              const int* __restrict__ batch,
                                              unsigned* __restrict__ g,
                                              int layer2) {
    int lane = threadIdx.x & 63;
    int node = __builtin_amdgcn_readfirstlane(blockIdx.x * 4 + (threadIdx.x >> 6));
    unsigned start = (node == 0) ? 0u : ends[node - 1];
    int deg = (int)(ends[node] - start);
    int row = lane & 15;       // A row (edge within tile)
    int j0 = (lane >> 4) << 3; // k-block start (channel j for t-generation)
    // B fragments (per-lane; 4KB/layer, L1-resident across waves)
    ABfrag b0h, b0l, b1h, b1l;
    {
        const uint4* W4 = (const uint4*)WpkL;
        *(uint4*)b0h.u = W4[0 * 64 + lane];
        *(uint4*)b0l.u = W4[1 * 64 + lane];
        *(uint4*)b1h.u = W4[2 * 64 + lane];
        *(uint4*)b1l.u = W4[3 * 64 + lane];
    }
    float pd0 = pos[3 * node], pd1 = pos[3 * node + 1], pd2 = pos[3 * node + 2];
    float fd[8];
#pragma unroll
    for (int q = 0; q < 8; q++)
        fd[q] = fmaf(pd0, Wf[j0 + q],
                fmaf(pd1, Wf[32 + j0 + q], pd2 * Wf[64 + j0 + q]));
    f32x4 vmax0 = {-3.0e38f, -3.0e38f, -3.0e38f, -3.0e38f};
    f32x4 vmax1 = vmax0;
    const f32x4 z = {0.f, 0.f, 0.f, 0.f};
    for (int i0 = 0; i0 < deg; i0 += 16) {
        int e = i0 + row;
        if (e >= deg) e = deg - 1;            // duplicate-pad (max-safe)
        int s = (int)srcS[start + e];
        const float* er = E + ((size_t)s << 5) + j0;
        float4 t0 = *(const float4*)er;
        float4 t1 = *(const float4*)(er + 4);
        float t[8] = {t0.x, t0.y, t0.z, t0.w, t1.x, t1.y, t1.z, t1.w};
        ABfrag ah, al;
#pragma unroll
        for (int w = 0; w < 4; w++) {
            float x0 = fmaxf(t[2 * w]     - fd[2 * w],     0.f);
            float x1 = fmaxf(t[2 * w + 1] - fd[2 * w + 1], 0.f);
            unsigned u0 = __float_as_uint(x0), u1 = __float_as_uint(x1);
            ah.u[w] = __builtin_amdgcn_perm(u1, u0, 0x07060302u);
            float r0 = x0 - __uint_as_float(u0 & 0xffff0000u);
            float r1 = x1 - __uint_as_float(u1 & 0xffff0000u);
            al.u[w] = __builtin_amdgcn_perm(__float_as_uint(r1),
                                            __float_as_uint(r0), 0x07060302u);
        }
        f32x4 acc0 = __builtin_amdgcn_mfma_f32_16x16x32_bf16(ah.v, b0h.v, z, 0, 0, 0);
        acc0 = __builtin_amdgcn_mfma_f32_16x16x32_bf16(al.v, b0h.v, acc0, 0, 0, 0);
        acc0 = __builtin_amdgcn_mfma_f32_16x16x32_bf16(ah.v, b0l.v, acc0, 0, 0, 0);
        f32x4 acc1 = __builtin_amdgcn_mfma_f32_16x16x32_bf16(ah.v, b1h.v, z, 0, 0, 0);
        acc1 = __builtin_amdgcn_mfma_f32_16x16x32_bf16(al.v, b1h.v, acc1, 0, 0, 0);
        acc1 = __builtin_amdgcn_mfma_f32_16x16x32_bf16(ah.v, b1l.v, acc1, 0, 0, 0);
#pragma unroll
        for (int r = 0; r < 4; r++) {
            vmax0[r] = fmaxf(vmax0[r], acc0[r]);
            vmax1[r] = fmaxf(vmax1[r], acc1[r]);
        }
    }
    // reduce max over the 16 edge-rows: 4 local regs, then groups via xor16/32
    float m0 = fmaxf(fmaxf(vmax0[0], vmax0[1]), fmaxf(vmax0[2], vmax0[3]));
    float m1 = fmaxf(fmaxf(vmax1[0], vmax1[1]), fmaxf(vmax1[2], vmax1[3]));
    m0 = fmaxf(m0, __shfl_xor(m0, 16));
    m0 = fmaxf(m0, __shfl_xor(m0, 32));
    m1 = fmaxf(m1, __shfl_xor(m1, 16));
    m1 = fmaxf(m1, __shfl_xor(m1, 32));
    if (lane < H) {
        float red = (lane < 16) ? m0 : m1;            // ch = lane (0..31)
        float val = (deg > 0) ? fmaxf(red + bb[lane], 0.f) : 0.f;
        if (!layer2) {
            aggOut[(size_t)node * H + lane] = val;    // h1 (relu folded)
        } else {
            int b = batch[node];
            unsigned bits = __float_as_uint(val);     // nonneg: bit order = value
            unsigned* gb = g + ((size_t)b << 5) + lane;
            if (bits > *gb) atomicMax(gb, bits);
        }
    }
}

__global__ __launch_bounds__(256) void k_out(const unsigned* __restrict__ g,
                                             const float* __restrict__ Wout,
                                             const float* __restrict__ bout,
                                             float* __restrict__ out) {
    int bidx = threadIdx.x;  // one block of 256
    float acc = bout[0];
#pragma unroll
    for (int k = 0; k < H; k++)
        acc = fmaf(__uint_as_float(g[bidx * H + k]), Wout[k], acc);
    out[bidx] = acc;
}

extern "C" void kernel_launch(void* const* d_in, const int* in_sizes, int n_in,
                              void* d_out, int out_size, void* d_ws, size_t ws_size,
                              hipStream_t stream) {
    const float* pos  = (const float*)d_in[0];
    const int* src    = (const int*)d_in[1];
    const int* dst    = src + NE;
    const int* batch  = (const int*)d_in[2];
    const float* W1a  = (const float*)d_in[3];
    const float* b1a  = (const float*)d_in[4];
    const float* W1b  = (const float*)d_in[5];
    const float* b1b  = (const float*)d_in[6];
    const float* W2a  = (const float*)d_in[7];
    const float* b2a  = (const float*)d_in[8];
    const float* W2b  = (const float*)d_in[9];
    const float* b2b  = (const float*)d_in[10];
    const float* Wout = (const float*)d_in[11];
    const float* bout = (const float*)d_in[12];
    float* out = (float*)d_out;

    const size_t SZ = (size_t)NN * H;  // 3.2M words
    float*    agg  = (float*)d_ws;                   // 12.8 MB (h1)
    float*    E    = (float*)d_ws + SZ;              // 12.8 MB (E1 then E2)
    unsigned* srcS = (unsigned*)d_ws + 2 * SZ;       // 12.8 MB (dst-sorted src)
    unsigned* g    = (unsigned*)d_ws + 3 * SZ;       // 32 KB (pool)
    unsigned* ends = g + NG * H;                     // 400 KB (CSR ends)
    unsigned* bsum = ends + NN;                      // scan partials
    unsigned* bpre = bsum + SB + 1;
    unsigned* Wpk  = bpre + SB + 1;                  // 16 KB (B-fragments)
    // Sort-phase temporaries aliased into agg's space (agg first written by
    // k_edge layer-1, which runs after the sort is complete):
    unsigned* hist    = (unsigned*)agg;
    unsigned* pre     = hist + NN;
    unsigned* cursors = pre + NN;

    const int EDGE_BLOCKS = NE / 256;   // 12500
    const int NODE_BLOCKS = SB;         // 391
    const int WAVE_BLOCKS = NN / 4;     // 25000 (4 node-waves per block, exact)

    k_init<<<NODE_BLOCKS, 256, 0, stream>>>(g, hist);
    k_packw<<<1, 64, 0, stream>>>(W1b, W2b, Wpk);
    k_hist<<<EDGE_BLOCKS, 256, 0, stream>>>(dst, hist);
    k_scan1<<<NODE_BLOCKS, 256, 0, stream>>>(hist, pre, bsum);
    k_scan2<<<1, 512, 0, stream>>>(bsum, bpre);
    k_scan3<<<NODE_BLOCKS, 256, 0, stream>>>(pre, bpre, hist, cursors, ends);
    k_scatter<<<EDGE_BLOCKS, 256, 0, stream>>>(src, dst, cursors, srcS);
    k_pre1<<<NODE_BLOCKS, 256, 0, stream>>>(pos, W1a, b1a, E);
    k_edge<<<WAVE_BLOCKS, 256, 0, stream>>>(srcS, ends, pos, E,
                                            W1a + 3 * H, Wpk, b1b,
                                            agg, batch, g, 0);
    k_pre2<<<NODE_BLOCKS, 256, 0, stream>>>(pos, agg, W2a, b2a, E);
    k_edge<<<WAVE_BLOCKS, 256, 0, stream>>>(srcS, ends, pos, E,
                                            W2a + 32 * H, Wpk + 1024, b2b,
                                            agg, batch, g, 1);
    k_out<<<1, 256, 0, stream>>>(g, Wout, bout, out);
}

// Round 14
// 655.665 us; speedup vs baseline: 3.0265x; 1.1565x over previous
//
#include <hip/hip_runtime.h>

#define NN 100000
#define NE 3200000
#define NG 256
#define H 32
#define SB ((NN + 255) / 256)    // 391 scan blocks
#define NB 98                    // dst buckets: (99999>>10)+1
#define BK_SH 10
#define PART_BLOCKS ((NE + 4095) / 4096)   // 782

typedef __attribute__((ext_vector_type(8))) short b16x8;   // 8 bf16 = 4 VGPRs
typedef __attribute__((ext_vector_type(4))) float f32x4;

union ABfrag { unsigned u[4]; b16x8 v; };

// init g=0 (pool accumulator; pooled values >=0 so raw-bit u32 max works),
// hist=0, bktcnt=0. Grid 391x256 covers NN.
__global__ __launch_bounds__(256) void k_init(unsigned* __restrict__ g,
                                              unsigned* __restrict__ hist,
                                              unsigned* __restrict__ bktcnt) {
    int i = blockIdx.x * 256 + threadIdx.x;
    if (i < NG * H) g[i] = 0u;
    if (i < NN) hist[i] = 0u;
    if (i < NB) bktcnt[i] = 0u;
}

// Pack Wb (32x32) of both layers into MFMA B-fragments, bf16 hi/lo split.
// B[k][n] for half h: value W[k*32 + h*16 + n]; lane l holds col n=l&15,
// k = 8*(l>>4)+i (pairs packed low-short-first).
__global__ __launch_bounds__(64) void k_packw(const float* __restrict__ W1b,
                                              const float* __restrict__ W2b,
                                              unsigned* __restrict__ Wpk) {
    int l = threadIdx.x;
    int n = l & 15, gq = l >> 4;
    for (int layer = 0; layer < 2; layer++) {
        const float* W = layer ? W2b : W1b;
        for (int h = 0; h < 2; h++) {
            unsigned hi[8], lo[8];
#pragma unroll
            for (int i = 0; i < 8; i++) {
                float w = W[(8 * gq + i) * H + h * 16 + n];
                unsigned wb = __float_as_uint(w);
                unsigned hb = wb & 0xffff0000u;
                float r = w - __uint_as_float(hb);
                hi[i] = hb;
                lo[i] = __float_as_uint(r) & 0xffff0000u;
            }
            unsigned* dh = Wpk + (((layer * 4 + h * 2 + 0) * 64) + l) * 4;
            unsigned* dl = Wpk + (((layer * 4 + h * 2 + 1) * 64) + l) * 4;
#pragma unroll
            for (int w2 = 0; w2 < 4; w2++) {
                dh[w2] = (hi[2 * w2] >> 16) | (hi[2 * w2 + 1] & 0xffff0000u);
                dl[w2] = (lo[2 * w2] >> 16) | (lo[2 * w2 + 1] & 0xffff0000u);
            }
        }
    }
}

// Per-dst histogram + per-bucket counts (LDS-accumulated, one flush per block).
__global__ __launch_bounds__(256) void k_hist(const int* __restrict__ dst,
                                              unsigned* __restrict__ hist,
                                              unsigned* __restrict__ bktcnt) {
    __shared__ unsigned lb[NB];
    int tid = threadIdx.x;
    if (tid < NB) lb[tid] = 0u;
    __syncthreads();
    int base = blockIdx.x * 4096 + tid;
    for (int c = 0; c < 16; c++) {
        int e = base + c * 256;
        if (e < NE) {
            int d = dst[e];
            atomicAdd(&hist[d], 1u);
            atomicAdd(&lb[d >> BK_SH], 1u);
        }
    }
    __syncthreads();
    if (tid < NB) {
        unsigned v = lb[tid];
        if (v) atomicAdd(&bktcnt[tid], v);
    }
}

// Block-level exclusive scan (Hillis-Steele in LDS), 256 elems/block.
__global__ __launch_bounds__(256) void k_scan1(const unsigned* __restrict__ hist,
                                               unsigned* __restrict__ pre,
                                               unsigned* __restrict__ bsum) {
    __shared__ unsigned sd[256];
    int tid = threadIdx.x;
    int i = blockIdx.x * 256 + tid;
    unsigned v = (i < NN) ? hist[i] : 0u;
    sd[tid] = v;
    __syncthreads();
    for (int off = 1; off < 256; off <<= 1) {
        unsigned t = (tid >= off) ? sd[tid - off] : 0u;
        __syncthreads();
        sd[tid] += t;
        __syncthreads();
    }
    if (i < NN) pre[i] = sd[tid] - v;
    if (tid == 255) bsum[blockIdx.x] = sd[255];
}

__global__ __launch_bounds__(512) void k_scan2(const unsigned* __restrict__ bsum,
                                               unsigned* __restrict__ bpre) {
    __shared__ unsigned sd[512];
    int t = threadIdx.x;
    unsigned v = (t < SB) ? bsum[t] : 0u;
    sd[t] = v;
    __syncthreads();
    for (int off = 1; off < 512; off <<= 1) {
        unsigned x = (t >= off) ? sd[t - off] : 0u;
        __syncthreads();
        sd[t] += x;
        __syncthreads();
    }
    if (t < SB) bpre[t] = sd[t] - v;
}

// cursors[i] = CSR start (scatter cursor for pass B); ends[i] = start+count.
__global__ __launch_bounds__(256) void k_scan3(const unsigned* __restrict__ pre,
                                               const unsigned* __restrict__ bpre,
                                               const unsigned* __restrict__ hist,
                                               unsigned* __restrict__ cursors,
                                               unsigned* __restrict__ ends) {
    int i = blockIdx.x * 256 + threadIdx.x;
    if (i < NN) {
        unsigned o = pre[i] + bpre[blockIdx.x];
        cursors[i] = o;
        ends[i] = o + hist[i];
    }
}

// Tiny exclusive scan of the 98 bucket counts (1 block of 128).
__global__ __launch_bounds__(128) void k_bscan(const unsigned* __restrict__ bktcnt,
                                               unsigned* __restrict__ bktbase,
                                               unsigned* __restrict__ bktcur) {
    __shared__ unsigned sd[128];
    int t = threadIdx.x;
    unsigned v = (t < NB) ? bktcnt[t] : 0u;
    sd[t] = v;
    __syncthreads();
    for (int off = 1; off < 128; off <<= 1) {
        unsigned x = (t >= off) ? sd[t - off] : 0u;
        __syncthreads();
        sd[t] += x;
        __syncthreads();
    }
    if (t < NB) { bktbase[t] = sd[t] - v; bktcur[t] = sd[t] - v; }
    if (t == 127) bktbase[NB] = NE;
}

// Pass A: partition edges into 98 dst-buckets. Per-block LDS hist -> one global
// reservation per bucket -> grouped staging writes (~168B runs; near-full lines).
// staging word = (src << 10) | (dst & 1023); bucket implicit from segment.
__global__ __launch_bounds__(256) void k_part(const int* __restrict__ src,
                                              const int* __restrict__ dst,
                                              unsigned* __restrict__ bktcur,
                                              unsigned* __restrict__ staging) {
    __shared__ unsigned lh[NB], lcur[NB];
    int tid = threadIdx.x;
    if (tid < NB) lh[tid] = 0u;
    __syncthreads();
    int base = blockIdx.x * 4096 + tid;
    for (int c = 0; c < 16; c++) {
        int e = base + c * 256;
        if (e < NE) atomicAdd(&lh[dst[e] >> BK_SH], 1u);
    }
    __syncthreads();
    if (tid < NB) {
        unsigned v = lh[tid];
        lcur[tid] = v ? atomicAdd(&bktcur[tid], v) : 0u;
    }
    __syncthreads();
    for (int c = 0; c < 16; c++) {
        int e = base + c * 256;
        if (e < NE) {
            int d = dst[e], s = src[e];
            unsigned off = atomicAdd(&lcur[d >> BK_SH], 1u);
            staging[off] = ((unsigned)s << BK_SH) | (unsigned)(d & ((1 << BK_SH) - 1));
        }
    }
}

// Pass B: staging (sequential read) -> final dst-sorted srcS. Each bucket's
// writes land in a 128KB srcS window (L2-resident) -> ~no write amplification.
__global__ __launch_bounds__(256) void k_scat2(const unsigned* __restrict__ staging,
                                               const unsigned* __restrict__ bktbase,
                                               unsigned* __restrict__ cursors,
                                               unsigned* __restrict__ srcS) {
    int i = blockIdx.x * 256 + threadIdx.x;   // grid covers exactly NE
    unsigned p = staging[i];
    int lo = 0, hi = NB - 1;                  // find b: bktbase[b] <= i < [b+1]
    while (lo < hi) {
        int mid = (lo + hi + 1) >> 1;
        if ((unsigned)i >= bktbase[mid]) lo = mid; else hi = mid - 1;
    }
    int d = (lo << BK_SH) | (int)(p & ((1u << BK_SH) - 1));
    unsigned slot = atomicAdd(&cursors[d], 1u);
    srcS[slot] = p >> BK_SH;
}

// Layer-1 src-side precompute:
//   E1[n][k] = b1a[k] + sum_i pos[n][i]*(W1a[i][k] + W1a[3+i][k])
__global__ __launch_bounds__(256) void k_pre1(const float* __restrict__ pos,
                                              const float* __restrict__ W1a,
                                              const float* __restrict__ b1a,
                                              float* __restrict__ E) {
    int n = blockIdx.x * 256 + threadIdx.x;
    if (n >= NN) return;
    float p0 = pos[3 * n], p1 = pos[3 * n + 1], p2 = pos[3 * n + 2];
    float ev[H];
#pragma unroll
    for (int k = 0; k < H; k++) {
        float v = b1a[k];
        v = fmaf(p0, W1a[k] + W1a[96 + k], v);
        v = fmaf(p1, W1a[32 + k] + W1a[128 + k], v);
        v = fmaf(p2, W1a[64 + k] + W1a[160 + k], v);
        ev[k] = v;
    }
    float4* E4 = (float4*)(E + (size_t)n * H);
#pragma unroll
    for (int r = 0; r < 8; r++)
        E4[r] = make_float4(ev[4 * r], ev[4 * r + 1], ev[4 * r + 2], ev[4 * r + 3]);
}

// Layer-2 src-side precompute: E2[n][k] = b2a[k] + h1[n]@W2a[0:32][k]
//   + pos[n]@W2a[32:35][k]
__global__ __launch_bounds__(256) void k_pre2(const float* __restrict__ pos,
                                              const float* __restrict__ agg,
                                              const float* __restrict__ W2a,
                                              const float* __restrict__ b2a,
                                              float* __restrict__ E) {
    int n = blockIdx.x * 256 + threadIdx.x;
    if (n >= NN) return;
    float h[H];
    const float4* A4 = (const float4*)(agg + (size_t)n * H);
#pragma unroll
    for (int r = 0; r < 8; r++) {
        float4 u = A4[r];
        h[4 * r + 0] = u.x; h[4 * r + 1] = u.y;
        h[4 * r + 2] = u.z; h[4 * r + 3] = u.w;
    }
    float p0 = pos[3 * n], p1 = pos[3 * n + 1], p2 = pos[3 * n + 2];
    float ev[H];
#pragma unroll
    for (int k = 0; k < H; k++) {
        float v = b2a[k];
        v = fmaf(p0, W2a[32 * H + k], v);
        v = fmaf(p1, W2a[33 * H + k], v);
        v = fmaf(p2, W2a[34 * H + k], v);
        ev[k] = v;
    }
#pragma unroll
    for (int j = 0; j < H; j++) {
        float hj = h[j];
#pragma unroll
        for (int k = 0; k < H; k++) ev[k] = fmaf(hj, W2a[j * H + k], ev[k]);
    }
    float4* E4 = (float4*)(E + (size_t)n * H);
#pragma unroll
    for (int r = 0; r < 8; r++)
        E4[r] = make_float4(ev[4 * r], ev[4 * r + 1], ev[4 * r + 2], ev[4 * r + 3]);
}

// MFMA edge kernel: ONE WAVE PER NODE, 16 EDGES PER TILE (unchanged from r13).
__global__ __launch_bounds__(256) void k_edge(const unsigned* __restrict__ srcS,
                                              const unsigned* __restrict__ ends,
                                              const float* __restrict__ pos,
                                              const float* __restrict__ E,
                                              const float* __restrict__ Wf,
                                              const unsigned* __restrict__ WpkL,
                                              const float* __restrict__ bb,
                                              float* __restrict__ aggOut,
                                              const int* __restrict__ batch,
                                              unsigned* __restrict__ g,
                                              int layer2) {
    int lane = threadIdx.x & 63;
    int node = __builtin_amdgcn_readfirstlane(blockIdx.x * 4 + (threadIdx.x >> 6));
    unsigned start = (node == 0) ? 0u : ends[node - 1];
    int deg = (int)(ends[node] - start);
    int row = lane & 15;       // A row (edge within tile)
    int j0 = (lane >> 4) << 3; // k-block start (channel j for t-generation)
    ABfrag b0h, b0l, b1h, b1l;
    {
        const uint4* W4 = (const uint4*)WpkL;
        *(uint4*)b0h.u = W4[0 * 64 + lane];
        *(uint4*)b0l.u = W4[1 * 64 + lane];
        *(uint4*)b1h.u = W4[2 * 64 + lane];
        *(uint4*)b1l.u = W4[3 * 64 + lane];
    }
    float pd0 = pos[3 * node], pd1 = pos[3 * node + 1], pd2 = pos[3 * node + 2];
    float fd[8];
#pragma unroll
    for (int q = 0; q < 8; q++)
        fd[q] = fmaf(pd0, Wf[j0 + q],
                fmaf(pd1, Wf[32 + j0 + q], pd2 * Wf[64 + j0 + q]));
    f32x4 vmax0 = {-3.0e38f, -3.0e38f, -3.0e38f, -3.0e38f};
    f32x4 vmax1 = vmax0;
    const f32x4 z = {0.f, 0.f, 0.f, 0.f};
    for (int i0 = 0; i0 < deg; i0 += 16) {
        int e = i0 + row;
        if (e >= deg) e = deg - 1;            // duplicate-pad (max-safe)
        int s = (int)srcS[start + e];
        const float* er = E + ((size_t)s << 5) + j0;
        float4 t0 = *(const float4*)er;
        float4 t1 = *(const float4*)(er + 4);
        float t[8] = {t0.x, t0.y, t0.z, t0.w, t1.x, t1.y, t1.z, t1.w};
        ABfrag ah, al;
#pragma unroll
        for (int w = 0; w < 4; w++) {
            float x0 = fmaxf(t[2 * w]     - fd[2 * w],     0.f);
            float x1 = fmaxf(t[2 * w + 1] - fd[2 * w + 1], 0.f);
            unsigned u0 = __float_as_uint(x0), u1 = __float_as_uint(x1);
            ah.u[w] = __builtin_amdgcn_perm(u1, u0, 0x07060302u);
            float r0 = x0 - __uint_as_float(u0 & 0xffff0000u);
            float r1 = x1 - __uint_as_float(u1 & 0xffff0000u);
            al.u[w] = __builtin_amdgcn_perm(__float_as_uint(r1),
                                            __float_as_uint(r0), 0x07060302u);
        }
        f32x4 acc0 = __builtin_amdgcn_mfma_f32_16x16x32_bf16(ah.v, b0h.v, z, 0, 0, 0);
        acc0 = __builtin_amdgcn_mfma_f32_16x16x32_bf16(al.v, b0h.v, acc0, 0, 0, 0);
        acc0 = __builtin_amdgcn_mfma_f32_16x16x32_bf16(ah.v, b0l.v, acc0, 0, 0, 0);
        f32x4 acc1 = __builtin_amdgcn_mfma_f32_16x16x32_bf16(ah.v, b1h.v, z, 0, 0, 0);
        acc1 = __builtin_amdgcn_mfma_f32_16x16x32_bf16(al.v, b1h.v, acc1, 0, 0, 0);
        acc1 = __builtin_amdgcn_mfma_f32_16x16x32_bf16(ah.v, b1l.v, acc1, 0, 0, 0);
#pragma unroll
        for (int r = 0; r < 4; r++) {
            vmax0[r] = fmaxf(vmax0[r], acc0[r]);
            vmax1[r] = fmaxf(vmax1[r], acc1[r]);
        }
    }
    float m0 = fmaxf(fmaxf(vmax0[0], vmax0[1]), fmaxf(vmax0[2], vmax0[3]));
    float m1 = fmaxf(fmaxf(vmax1[0], vmax1[1]), fmaxf(vmax1[2], vmax1[3]));
    m0 = fmaxf(m0, __shfl_xor(m0, 16));
    m0 = fmaxf(m0, __shfl_xor(m0, 32));
    m1 = fmaxf(m1, __shfl_xor(m1, 16));
    m1 = fmaxf(m1, __shfl_xor(m1, 32));
    if (lane < H) {
        float red = (lane < 16) ? m0 : m1;            // ch = lane (0..31)
        float val = (deg > 0) ? fmaxf(red + bb[lane], 0.f) : 0.f;
        if (!layer2) {
            aggOut[(size_t)node * H + lane] = val;    // h1 (relu folded)
        } else {
            int b = batch[node];
            unsigned bits = __float_as_uint(val);     // nonneg: bit order = value
            unsigned* gb = g + ((size_t)b << 5) + lane;
            if (bits > *gb) atomicMax(gb, bits);
        }
    }
}

__global__ __launch_bounds__(256) void k_out(const unsigned* __restrict__ g,
                                             const float* __restrict__ Wout,
                                             const float* __restrict__ bout,
                                             float* __restrict__ out) {
    int bidx = threadIdx.x;  // one block of 256
    float acc = bout[0];
#pragma unroll
    for (int k = 0; k < H; k++)
        acc = fmaf(__uint_as_float(g[bidx * H + k]), Wout[k], acc);
    out[bidx] = acc;
}

extern "C" void kernel_launch(void* const* d_in, const int* in_sizes, int n_in,
                              void* d_out, int out_size, void* d_ws, size_t ws_size,
                              hipStream_t stream) {
    const float* pos  = (const float*)d_in[0];
    const int* src    = (const int*)d_in[1];
    const int* dst    = src + NE;
    const int* batch  = (const int*)d_in[2];
    const float* W1a  = (const float*)d_in[3];
    const float* b1a  = (const float*)d_in[4];
    const float* W1b  = (const float*)d_in[5];
    const float* b1b  = (const float*)d_in[6];
    const float* W2a  = (const float*)d_in[7];
    const float* b2a  = (const float*)d_in[8];
    const float* W2b  = (const float*)d_in[9];
    const float* b2b  = (const float*)d_in[10];
    const float* Wout = (const float*)d_in[11];
    const float* bout = (const float*)d_in[12];
    float* out = (float*)d_out;

    const size_t SZ = (size_t)NN * H;  // 3.2M words
    float*    agg  = (float*)d_ws;                   // 12.8 MB (h1)
    float*    E    = (float*)d_ws + SZ;              // 12.8 MB (E1/E2)
    unsigned* srcS = (unsigned*)d_ws + 2 * SZ;       // 12.8 MB (dst-sorted src)
    unsigned* g    = (unsigned*)d_ws + 3 * SZ;       // 32 KB (pool)
    unsigned* ends = g + NG * H;                     // 400 KB (CSR ends)
    unsigned* bsum = ends + NN;                      // scan partials
    unsigned* bpre = bsum + SB + 1;
    unsigned* Wpk  = bpre + SB + 1;                  // 16 KB (B-fragments)
    unsigned* bktcnt  = Wpk + 4096;                  // NB
    unsigned* bktbase = bktcnt + NB;                 // NB+1
    unsigned* bktcur  = bktbase + NB + 1;            // NB
    // Aliased temporaries:
    //   agg's space (dead until k_edge L1): hist, pre, cursors
    //   E's space   (dead until k_pre1):    staging (NE u32 == SZ exactly)
    unsigned* hist    = (unsigned*)agg;
    unsigned* pre     = hist + NN;
    unsigned* cursors = pre + NN;
    unsigned* staging = (unsigned*)E;

    const int NODE_BLOCKS = SB;          // 391
    const int SCAT_BLOCKS = NE / 256;    // 12500 (k_scat2, exact)
    const int WAVE_BLOCKS = NN / 4;      // 25000 (4 node-waves/block, exact)

    k_init<<<NODE_BLOCKS, 256, 0, stream>>>(g, hist, bktcnt);
    k_packw<<<1, 64, 0, stream>>>(W1b, W2b, Wpk);
    k_hist<<<PART_BLOCKS, 256, 0, stream>>>(dst, hist, bktcnt);
    k_scan1<<<NODE_BLOCKS, 256, 0, stream>>>(hist, pre, bsum);
    k_scan2<<<1, 512, 0, stream>>>(bsum, bpre);
    k_scan3<<<NODE_BLOCKS, 256, 0, stream>>>(pre, bpre, hist, cursors, ends);
    k_bscan<<<1, 128, 0, stream>>>(bktcnt, bktbase, bktcur);
    k_part<<<PART_BLOCKS, 256, 0, stream>>>(src, dst, bktcur, staging);
    k_scat2<<<SCAT_BLOCKS, 256, 0, stream>>>(staging, bktbase, cursors, srcS);
    k_pre1<<<NODE_BLOCKS, 256, 0, stream>>>(pos, W1a, b1a, E);
    k_edge<<<WAVE_BLOCKS, 256, 0, stream>>>(srcS, ends, pos, E,
                                            W1a + 3 * H, Wpk, b1b,
                                            agg, batch, g, 0);
    k_pre2<<<NODE_BLOCKS, 256, 0, stream>>>(pos, agg, W2a, b2a, E);
    k_edge<<<WAVE_BLOCKS, 256, 0, stream>>>(srcS, ends, pos, E,
                                            W2a + 32 * H, Wpk + 1024, b2b,
                                            agg, batch, g, 1);
    k_out<<<1, 256, 0, stream>>>(g, Wout, bout, out);
}